// Round 1
// baseline (25.169 us; speedup 1.0000x reference)
//
#include <hip/hip_runtime.h>
#include <hip/hip_bf16.h>

// Embedding gather: out[t, :] = W[ids[t], :]
// ids: [4*4096] int32, W: [50257, 1024] fp32, out: [16384, 1024] fp32.
// One block (256 threads) per token row; each thread moves one float4
// (16B) -> 4 KB per row, fully coalesced on both read and write.
__global__ __launch_bounds__(256) void Embedding_88227218195299_kernel(
    const int* __restrict__ ids,
    const float4* __restrict__ W,     // row = 256 float4
    float4* __restrict__ out,         // row = 256 float4
    int n_tokens)
{
    int row = blockIdx.x;
    if (row >= n_tokens) return;
    int tok = ids[row];                       // block-uniform -> scalar load
    const float4* __restrict__ src = W + (size_t)tok * 256;
    float4* __restrict__ dst = out + (size_t)row * 256;
    dst[threadIdx.x] = src[threadIdx.x];
}

extern "C" void kernel_launch(void* const* d_in, const int* in_sizes, int n_in,
                              void* d_out, int out_size, void* d_ws, size_t ws_size,
                              hipStream_t stream) {
    const int*   ids = (const int*)d_in[0];
    const float* W   = (const float*)d_in[1];
    float*       out = (float*)d_out;

    const int n_tokens = in_sizes[0];          // 4 * 4096 = 16384
    // D_MODEL = 1024 floats = 256 float4 per row (fixed by the problem).

    dim3 grid(n_tokens);
    dim3 block(256);
    Embedding_88227218195299_kernel<<<grid, block, 0, stream>>>(
        ids,
        (const float4*)W,
        (float4*)out,
        n_tokens);
}